// Round 7
// baseline (709.458 us; speedup 1.0000x reference)
//
#include <hip/hip_runtime.h>
#include <math.h>

// Problem constants (B=2, T=4096, n=4, D=2048)
#define DM      8192      // n*D flattened feature dim
#define NK      24        // 4 pre + 4 post + 16 res dot products
#define NACC    25        // + 1 for sum(x^2)
#define NTOK    8192      // B*T tokens
#define NGRP    32        // d-groups across blocks
#define DPG     256       // d per group (weights LDS-resident: 24 KB)
#define TPB     256
#define TOKB    128       // tokens per block (32 ts * 4 u)
#define UT      4         // tokens per thread
#define NCH     16        // chunks of 16 d; thread covers 4 d/chunk
#define KHN     12        // coefficients per kh half
#define PPT     28        // padded partials per token (25 used, float4-aligned)

// ---------------------------------------------------------------------------
// Kernel 1: Wc2[grp][k][dloc] = alpha_k * W_k[grp*256+dloc] * rms_w[...]
// ---------------------------------------------------------------------------
__global__ void combine_w(const float* __restrict__ rms_w,
                          const float* __restrict__ w_pre,
                          const float* __restrict__ w_post,
                          const float* __restrict__ w_res,
                          const float* __restrict__ a_pre,
                          const float* __restrict__ a_post,
                          const float* __restrict__ a_res,
                          float* __restrict__ Wc2) {
    int idx = blockIdx.x * blockDim.x + threadIdx.x;
    if (idx >= NGRP * NK * DPG) return;
    const int grp  = idx / (NK * DPG);
    const int r    = idx - grp * (NK * DPG);
    const int k    = r / DPG;
    const int dloc = r - k * DPG;
    const int d    = grp * DPG + dloc;
    float w, a;
    if (k < 4)      { w = w_pre [(size_t)k       * DM + d]; a = a_pre[0];  }
    else if (k < 8) { w = w_post[(size_t)(k - 4) * DM + d]; a = a_post[0]; }
    else            { w = w_res [(size_t)(k - 8) * DM + d]; a = a_res[0];  }
    Wc2[idx] = a * w * rms_w[d];
}

// async global->LDS, 16B per lane (dest linear: wave-uniform base + lane*16)
__device__ __forceinline__ void load_lds16(const float* g, float* l) {
    __builtin_amdgcn_global_load_lds(
        (const __attribute__((address_space(1))) void*)g,
        (__attribute__((address_space(3))) void*)l, 16, 0, 0);
}

// ---------------------------------------------------------------------------
// Kernel 2: streaming partials. Block = 128 tokens x 256 d.
//  thread (ts=t>>3, kh=(t>>2)&1, dl=t&3):
//    tokens {tile*128 + ts + 32u}, coeff half kh*12..+12 (+ ss, both halves),
//    d-slice dl*4 per 16-d chunk. acc[4][13] = 52 regs, statically indexed.
//  __launch_bounds__(256,4): VGPR cap 128 — register floor is ~100; (256,5)
//  capped at 48 VGPR and spilled (R5: 619us, 886 MB fetch). Do NOT raise.
//  x prefetch distance-2 via xa/xb ping-pong (unroll-2), no register copies.
// part layout (token-major, padded): part[(grp*NTOK + token)*28 + c]
// ---------------------------------------------------------------------------
__global__ __launch_bounds__(TPB, 4) void partial_k(const float* __restrict__ x,
                                                    const float* __restrict__ Wc2,
                                                    float* __restrict__ part) {
    __shared__ __align__(16) float wlds[NK * DPG];   // [24][256] k-major, 24 KB

    const int t    = threadIdx.x;
    const int tile = blockIdx.x;          // 0..63
    const int grp  = blockIdx.y;          // 0..31

    // ---- stage weights once: 24 KB linear ----
    const float* wsrc = Wc2 + (size_t)grp * (NK * DPG);
#pragma unroll
    for (int ld = 0; ld < 6; ++ld) {
        const int e = (t + ld * TPB) * 4;
        load_lds16(wsrc + e, &wlds[e]);
    }

    const int dl     = t & 3;             // d sublane 0..3
    const int kh     = (t >> 2) & 1;      // coefficient half 0..1
    const int ts     = t >> 3;            // token slot 0..31
    const int tok0   = tile * TOKB + ts;  // + 32*u
    const int khbase = kh * (KHN * DPG);
    const int dl4    = dl * 4;
    const float* xp  = x + (size_t)tok0 * DM + grp * DPG + dl4;

    float acc[UT][13];
#pragma unroll
    for (int u = 0; u < UT; ++u)
#pragma unroll
        for (int kk = 0; kk < 13; ++kk) acc[u][kk] = 0.0f;

    __syncthreads();                      // weights staged (drains vmcnt)

#define LOADX(buf, cidx) do {                                               \
    _Pragma("unroll")                                                       \
    for (int u = 0; u < UT; ++u) {                                          \
        const float4 v = *(const float4*)(xp + (size_t)u * 32 * DM +        \
                                          (cidx) * 16);                     \
        buf[u][0] = v.x; buf[u][1] = v.y; buf[u][2] = v.z; buf[u][3] = v.w; \
    }                                                                       \
} while (0)

#define COMPUTE(buf, cidx) do {                                             \
    const float* wl = &wlds[khbase + (cidx) * 16 + dl4];                    \
    _Pragma("unroll")                                                       \
    for (int kk = 0; kk < KHN; ++kk) {                                      \
        const float4 w4 = *(const float4*)(wl + kk * DPG);                  \
        _Pragma("unroll")                                                   \
        for (int u = 0; u < UT; ++u) {                                      \
            acc[u][kk] = fmaf(buf[u][0], w4.x, acc[u][kk]);                 \
            acc[u][kk] = fmaf(buf[u][1], w4.y, acc[u][kk]);                 \
            acc[u][kk] = fmaf(buf[u][2], w4.z, acc[u][kk]);                 \
            acc[u][kk] = fmaf(buf[u][3], w4.w, acc[u][kk]);                 \
        }                                                                   \
    }                                                                       \
    _Pragma("unroll")                                                       \
    for (int u = 0; u < UT; ++u) {                                          \
        acc[u][12] = fmaf(buf[u][0], buf[u][0], acc[u][12]);                \
        acc[u][12] = fmaf(buf[u][1], buf[u][1], acc[u][12]);                \
        acc[u][12] = fmaf(buf[u][2], buf[u][2], acc[u][12]);                \
        acc[u][12] = fmaf(buf[u][3], buf[u][3], acc[u][12]);                \
    }                                                                       \
} while (0)

    float xa[UT][4], xb[UT][4];
    LOADX(xa, 0);
    LOADX(xb, 1);

#pragma unroll 1
    for (int cc = 0; cc < NCH / 2; ++cc) {
        COMPUTE(xa, 2 * cc);
        if (cc + 1 < NCH / 2) LOADX(xa, 2 * cc + 2);   // uniform branch
        COMPUTE(xb, 2 * cc + 1);
        if (cc + 1 < NCH / 2) LOADX(xb, 2 * cc + 3);
    }
#undef LOADX
#undef COMPUTE

    // ---- butterfly reduce over the 4 dl lanes ----
#pragma unroll
    for (int u = 0; u < UT; ++u)
#pragma unroll
        for (int kk = 0; kk < 13; ++kk) {
            float v = acc[u][kk];
            v += __shfl_xor(v, 1);
            v += __shfl_xor(v, 2);
            acc[u][kk] = v;
        }

    // ---- reshape via LDS into token-major [128][28] (static reg indices) ----
    __syncthreads();                      // done reading wlds
    float* red = wlds;
    if (dl == 0) {
#pragma unroll
        for (int u = 0; u < UT; ++u) {
            const int tloc = ts + 32 * u;
#pragma unroll
            for (int kk = 0; kk < KHN; ++kk)
                red[tloc * PPT + kh * KHN + kk] = acc[u][kk];
            if (kh == 0) red[tloc * PPT + 24] = acc[u][12];
        }
    }
    __syncthreads();

    // ---- block-copy 128*28 floats = 896 float4 (contiguous global write) ----
    float4* dst = (float4*)(part + ((size_t)grp * NTOK + (size_t)tile * TOKB) * PPT);
    const float4* srcv = (const float4*)red;
#pragma unroll
    for (int w = 0; w < 4; ++w) {
        const int i = t + w * TPB;
        if (i < (TOKB * PPT) / 4) dst[i] = srcv[i];
    }
}

// ---------------------------------------------------------------------------
// Kernel 3: finalize. Block = 32 tokens x 8 grp-octant lanes (256 blocks).
// ---------------------------------------------------------------------------
__global__ void finalize_k(const float* __restrict__ part,
                           const float* __restrict__ b_pre,
                           const float* __restrict__ b_post,
                           const float* __restrict__ b_res,
                           float* __restrict__ out) {
    const int t  = threadIdx.x;
    const int gq = t & 7;
    const int ts = t >> 3;
    const int tk = blockIdx.x * 32 + ts;

    float v[NACC];
#pragma unroll
    for (int c = 0; c < NACC; ++c) v[c] = 0.0f;
#pragma unroll
    for (int gg = 0; gg < 4; ++gg) {
        const int g = gq * 4 + gg;
        const float4* p4 = (const float4*)(part + ((size_t)g * NTOK + tk) * PPT);
        const float4 a0 = p4[0], a1 = p4[1], a2 = p4[2], a3 = p4[3];
        const float4 a4 = p4[4], a5 = p4[5], a6 = p4[6];
        v[0] += a0.x;  v[1] += a0.y;  v[2] += a0.z;  v[3] += a0.w;
        v[4] += a1.x;  v[5] += a1.y;  v[6] += a1.z;  v[7] += a1.w;
        v[8] += a2.x;  v[9] += a2.y;  v[10] += a2.z; v[11] += a2.w;
        v[12] += a3.x; v[13] += a3.y; v[14] += a3.z; v[15] += a3.w;
        v[16] += a4.x; v[17] += a4.y; v[18] += a4.z; v[19] += a4.w;
        v[20] += a5.x; v[21] += a5.y; v[22] += a5.z; v[23] += a5.w;
        v[24] += a6.x;                 // a6.yzw = pad, ignored
    }
#pragma unroll
    for (int c = 0; c < NACC; ++c) {
        float s = v[c];
        s += __shfl_xor(s, 1);
        s += __shfl_xor(s, 2);
        s += __shfl_xor(s, 4);
        v[c] = s;
    }

    const float rstd = rsqrtf(v[24] * (1.0f / (float)DM) + 1e-6f);

    float hp[4], hq[4];
#pragma unroll
    for (int j = 0; j < 4; ++j) {
        const float lp = fmaf(v[j], rstd, b_pre[j]);
        hp[j] = 1.0f / (1.0f + expf(-lp));
        const float lq = fmaf(v[4 + j], rstd, b_post[j]);
        hq[j] = 2.0f / (1.0f + expf(-lq));
    }

    // Sinkhorn-Knopp on 4x4, in registers; v_rcp_f32 for the 160 divides
    // (abs margin 13x; rcp err ~1e-6 compounds to ~1e-5 over 40 passes)
    float M[4][4];
#pragma unroll
    for (int i = 0; i < 4; ++i) {
        float l[4];
#pragma unroll
        for (int j = 0; j < 4; ++j)
            l[j] = fmaf(v[8 + i * 4 + j], rstd, b_res[i * 4 + j]);
        const float m = fmaxf(fmaxf(l[0], l[1]), fmaxf(l[2], l[3]));
#pragma unroll
        for (int j = 0; j < 4; ++j)
            M[i][j] = fmaxf(expf(l[j] - m), 1e-6f);
    }
    for (int it = 0; it < 20; ++it) {
#pragma unroll
        for (int i = 0; i < 4; ++i) {
            const float s = (M[i][0] + M[i][1]) + (M[i][2] + M[i][3]);
            const float inv = __builtin_amdgcn_rcpf(fmaxf(s, 1e-6f));
#pragma unroll
            for (int j = 0; j < 4; ++j) M[i][j] *= inv;
        }
#pragma unroll
        for (int j = 0; j < 4; ++j) {
            const float s = (M[0][j] + M[1][j]) + (M[2][j] + M[3][j]);
            const float inv = __builtin_amdgcn_rcpf(fmaxf(s, 1e-6f));
#pragma unroll
            for (int i = 0; i < 4; ++i) M[i][j] *= inv;
        }
    }

    float* out_pre  = out;                        // [NTOK][4]
    float* out_post = out + (size_t)NTOK * 4;     // [NTOK][4]
    float* out_res  = out + (size_t)NTOK * 8;     // [NTOK][16]
    if (gq == 0) {
        ((float4*)out_pre)[tk] = make_float4(hp[0], hp[1], hp[2], hp[3]);
    } else if (gq == 1) {
        ((float4*)out_post)[tk] = make_float4(hq[0], hq[1], hq[2], hq[3]);
    } else if (gq >= 4) {
        const int i = gq - 4;
        ((float4*)out_res)[tk * 4 + i] =
            make_float4(M[i][0], M[i][1], M[i][2], M[i][3]);
    }
}

// ---------------------------------------------------------------------------
extern "C" void kernel_launch(void* const* d_in, const int* in_sizes, int n_in,
                              void* d_out, int out_size, void* d_ws, size_t ws_size,
                              hipStream_t stream) {
    const float* x      = (const float*)d_in[0];   // (2,4096,4,2048) fp32
    const float* rms_w  = (const float*)d_in[1];   // (8192,)
    const float* w_pre  = (const float*)d_in[2];   // (4,8192)
    const float* w_post = (const float*)d_in[3];   // (4,8192)
    const float* w_res  = (const float*)d_in[4];   // (16,8192)
    const float* b_pre  = (const float*)d_in[5];   // (4,)
    const float* b_post = (const float*)d_in[6];   // (4,)
    const float* b_res  = (const float*)d_in[7];   // (4,4)
    const float* a_pre  = (const float*)d_in[8];   // scalar
    const float* a_post = (const float*)d_in[9];   // scalar
    const float* a_res  = (const float*)d_in[10];  // scalar
    float* out = (float*)d_out;

    // ws: Wc2 (196608 floats) + part (32*8192*28 = 7.34M floats) ~ 30.2 MB
    float* Wc2  = (float*)d_ws;
    float* part = (float*)d_ws + (size_t)NGRP * NK * DPG;

    combine_w<<<(NGRP * NK * DPG + TPB - 1) / TPB, TPB, 0, stream>>>(
        rms_w, w_pre, w_post, w_res, a_pre, a_post, a_res, Wc2);

    partial_k<<<dim3(NTOK / TOKB, NGRP), TPB, 0, stream>>>(x, Wc2, part);

    finalize_k<<<NTOK / 32, TPB, 0, stream>>>(part, b_pre, b_post, b_res, out);
}

// Round 8
// 99.658 us; speedup vs baseline: 7.1189x; 7.1189x over previous
//
#include <hip/hip_runtime.h>
#include <math.h>

// Problem constants (B=2, T=4096, n=4, D=2048)
#define DM      8192      // n*D flattened feature dim
#define NK      24        // 4 pre + 4 post + 16 res dot products
#define NACC    25        // + 1 for sum(x^2)
#define NTOK    8192      // B*T tokens
#define NGRP    32        // d-groups across blocks
#define DPG     256       // d per group
#define TPB     256
#define TOKB    64        // tokens per block (16 ts * 4 u)
#define UT      4         // tokens per thread
#define NCH     16        // chunks of 16 d; thread covers 4 d/chunk
#define KQN     6         // coefficients per kq quarter
#define PADROW  260       // padded weight row stride (floats): bank-spreads kq
#define WLDN    (NK * PADROW)   // 6240 floats = 24960 B
#define PPT     28        // padded partials per token (25 used, float4-aligned)

// ---------------------------------------------------------------------------
// Kernel 1: Wc2[grp][k][col] = alpha_k * W_k[grp*256+col] * rms_w[...]
// Row stride PADROW=260 (cols 256..259 zeroed). Per-grp block is linear
// 24960 B so partial_k stages it with global_load_lds.
// ---------------------------------------------------------------------------
__global__ void combine_w(const float* __restrict__ rms_w,
                          const float* __restrict__ w_pre,
                          const float* __restrict__ w_post,
                          const float* __restrict__ w_res,
                          const float* __restrict__ a_pre,
                          const float* __restrict__ a_post,
                          const float* __restrict__ a_res,
                          float* __restrict__ Wc2) {
    int idx = blockIdx.x * blockDim.x + threadIdx.x;
    if (idx >= NGRP * WLDN) return;
    const int grp = idx / WLDN;
    const int r   = idx - grp * WLDN;
    const int k   = r / PADROW;
    const int col = r - k * PADROW;
    if (col >= DPG) { Wc2[idx] = 0.0f; return; }     // pad columns
    const int d = grp * DPG + col;
    float w, a;
    if (k < 4)      { w = w_pre [(size_t)k       * DM + d]; a = a_pre[0];  }
    else if (k < 8) { w = w_post[(size_t)(k - 4) * DM + d]; a = a_post[0]; }
    else            { w = w_res [(size_t)(k - 8) * DM + d]; a = a_res[0];  }
    Wc2[idx] = a * w * rms_w[d];
}

// async global->LDS, 16B per lane (dest linear: wave-uniform base + lane*16)
__device__ __forceinline__ void load_lds16(const float* g, float* l) {
    __builtin_amdgcn_global_load_lds(
        (const __attribute__((address_space(1))) void*)g,
        (__attribute__((address_space(3))) void*)l, 16, 0, 0);
}

// ---------------------------------------------------------------------------
// Kernel 2: streaming partials. Block = 64 tokens x 256 d.
//  thread (ts=t>>4, kq=(t>>2)&3, dl=t&3):
//    tokens {tile*64 + ts + 16u}, coeff quarter kq*6..+6 (+ ss, all lanes),
//    d-slice dl*4 per 16-d chunk. acc[4][7] = 28 regs -> live ~85, well
//    under the 128 cap: no spill, natural 5 waves/SIMD.
//  R5/R7 lessons: acc[4][13]=52 regs sat on the regalloc cliff (spilled at
//  64/48 VGPR). Do NOT raise min-waves arg; do NOT macro-restructure the
//  prefetch loop. Weight rows padded to 260 floats: per-kq bank offsets
//  {0,24,16,8} -> 2 addrs/bank on ds_read_b128 = conflict-free (m136).
// part layout (token-major, padded): part[(grp*NTOK + token)*28 + c]
// ---------------------------------------------------------------------------
__global__ __launch_bounds__(TPB, 4) void partial_k(const float* __restrict__ x,
                                                    const float* __restrict__ Wc2,
                                                    float* __restrict__ part) {
    __shared__ __align__(16) float wlds[WLDN];   // [24][260], 24960 B

    const int t    = threadIdx.x;
    const int tile = blockIdx.x;          // 0..127
    const int grp  = blockIdx.y;          // 0..31

    // ---- stage weights once: 24960 B linear (1560 x 16B units) ----
    const float* wsrc = Wc2 + (size_t)grp * WLDN;
#pragma unroll
    for (int ld = 0; ld < 6; ++ld) {
        const int e = (t + ld * TPB) * 4;
        load_lds16(wsrc + e, &wlds[e]);
    }
    if (t < 24) {                         // tail: units 1536..1559
        const int e = (1536 + t) * 4;
        load_lds16(wsrc + e, &wlds[e]);
    }

    const int dl   = t & 3;               // d sublane 0..3
    const int kq   = (t >> 2) & 3;        // coefficient quarter 0..3
    const int ts   = t >> 4;              // token slot 0..15
    const int tok0 = tile * TOKB + ts;    // + 16*u
    const int dl4  = dl * 4;
    const float* xp = x + (size_t)tok0 * DM + grp * DPG + dl4;
    const float* wq = wlds + kq * (KQN * PADROW);

    float acc[UT][7];
#pragma unroll
    for (int u = 0; u < UT; ++u)
#pragma unroll
        for (int kk = 0; kk < 7; ++kk) acc[u][kk] = 0.0f;

    __syncthreads();                      // weights staged (drains vmcnt)

    float xc[UT][4], xn[UT][4];
#pragma unroll
    for (int u = 0; u < UT; ++u) {
        const float4 v = *(const float4*)(xp + (size_t)u * 16 * DM);
        xc[u][0] = v.x; xc[u][1] = v.y; xc[u][2] = v.z; xc[u][3] = v.w;
    }

    for (int c = 0; c < NCH; ++c) {
        if (c + 1 < NCH) {                // uniform branch: prefetch next chunk
#pragma unroll
            for (int u = 0; u < UT; ++u) {
                const float4 v = *(const float4*)(xp + (size_t)u * 16 * DM +
                                                  (c + 1) * 16);
                xn[u][0] = v.x; xn[u][1] = v.y; xn[u][2] = v.z; xn[u][3] = v.w;
            }
        }
        const float* wl = wq + c * 16 + dl4;
#pragma unroll
        for (int kk = 0; kk < KQN; ++kk) {
            const float4 w4 = *(const float4*)(wl + kk * PADROW);
#pragma unroll
            for (int u = 0; u < UT; ++u) {
                acc[u][kk] = fmaf(xc[u][0], w4.x, acc[u][kk]);
                acc[u][kk] = fmaf(xc[u][1], w4.y, acc[u][kk]);
                acc[u][kk] = fmaf(xc[u][2], w4.z, acc[u][kk]);
                acc[u][kk] = fmaf(xc[u][3], w4.w, acc[u][kk]);
            }
        }
#pragma unroll
        for (int u = 0; u < UT; ++u)      // ss on all lanes (uniform)
#pragma unroll
            for (int e = 0; e < 4; ++e)
                acc[u][6] = fmaf(xc[u][e], xc[u][e], acc[u][6]);
        if (c + 1 < NCH) {
#pragma unroll
            for (int u = 0; u < UT; ++u)
#pragma unroll
                for (int e = 0; e < 4; ++e) xc[u][e] = xn[u][e];
        }
    }

    // ---- butterfly reduce over the 4 dl lanes ----
#pragma unroll
    for (int u = 0; u < UT; ++u)
#pragma unroll
        for (int kk = 0; kk < 7; ++kk) {
            float v = acc[u][kk];
            v += __shfl_xor(v, 1);
            v += __shfl_xor(v, 2);
            acc[u][kk] = v;
        }

    // ---- reshape via LDS into token-major [64][28] (static reg indices) ----
    __syncthreads();                      // done reading wlds
    float* red = wlds;
    if (dl == 0) {
#pragma unroll
        for (int u = 0; u < UT; ++u) {
            const int tloc = ts + 16 * u;
#pragma unroll
            for (int kk = 0; kk < KQN; ++kk)
                red[tloc * PPT + kq * KQN + kk] = acc[u][kk];
            if (kq == 0) red[tloc * PPT + 24] = acc[u][6];
        }
    }
    __syncthreads();

    // ---- block-copy 64*28 floats = 448 float4 (contiguous global write) ----
    float4* dst = (float4*)(part + ((size_t)grp * NTOK + (size_t)tile * TOKB) * PPT);
    const float4* srcv = (const float4*)red;
#pragma unroll
    for (int w = 0; w < 2; ++w) {
        const int i = t + w * TPB;
        if (i < (TOKB * PPT) / 4) dst[i] = srcv[i];
    }
}

// ---------------------------------------------------------------------------
// Kernel 3: finalize. Block = 32 tokens x 8 grp-octant lanes (256 blocks).
// ---------------------------------------------------------------------------
__global__ void finalize_k(const float* __restrict__ part,
                           const float* __restrict__ b_pre,
                           const float* __restrict__ b_post,
                           const float* __restrict__ b_res,
                           float* __restrict__ out) {
    const int t  = threadIdx.x;
    const int gq = t & 7;
    const int ts = t >> 3;
    const int tk = blockIdx.x * 32 + ts;

    float v[NACC];
#pragma unroll
    for (int c = 0; c < NACC; ++c) v[c] = 0.0f;
#pragma unroll
    for (int gg = 0; gg < 4; ++gg) {
        const int g = gq * 4 + gg;
        const float4* p4 = (const float4*)(part + ((size_t)g * NTOK + tk) * PPT);
        const float4 a0 = p4[0], a1 = p4[1], a2 = p4[2], a3 = p4[3];
        const float4 a4 = p4[4], a5 = p4[5], a6 = p4[6];
        v[0] += a0.x;  v[1] += a0.y;  v[2] += a0.z;  v[3] += a0.w;
        v[4] += a1.x;  v[5] += a1.y;  v[6] += a1.z;  v[7] += a1.w;
        v[8] += a2.x;  v[9] += a2.y;  v[10] += a2.z; v[11] += a2.w;
        v[12] += a3.x; v[13] += a3.y; v[14] += a3.z; v[15] += a3.w;
        v[16] += a4.x; v[17] += a4.y; v[18] += a4.z; v[19] += a4.w;
        v[20] += a5.x; v[21] += a5.y; v[22] += a5.z; v[23] += a5.w;
        v[24] += a6.x;                 // a6.yzw = pad, ignored
    }
#pragma unroll
    for (int c = 0; c < NACC; ++c) {
        float s = v[c];
        s += __shfl_xor(s, 1);
        s += __shfl_xor(s, 2);
        s += __shfl_xor(s, 4);
        v[c] = s;
    }

    const float rstd = rsqrtf(v[24] * (1.0f / (float)DM) + 1e-6f);

    float hp[4], hq[4];
#pragma unroll
    for (int j = 0; j < 4; ++j) {
        const float lp = fmaf(v[j], rstd, b_pre[j]);
        hp[j] = 1.0f / (1.0f + expf(-lp));
        const float lq = fmaf(v[4 + j], rstd, b_post[j]);
        hq[j] = 2.0f / (1.0f + expf(-lq));
    }

    // Sinkhorn-Knopp on 4x4, in registers; v_rcp_f32 for the 160 divides
    // (passed R7 with identical absmax 1.95e-3)
    float M[4][4];
#pragma unroll
    for (int i = 0; i < 4; ++i) {
        float l[4];
#pragma unroll
        for (int j = 0; j < 4; ++j)
            l[j] = fmaf(v[8 + i * 4 + j], rstd, b_res[i * 4 + j]);
        const float m = fmaxf(fmaxf(l[0], l[1]), fmaxf(l[2], l[3]));
#pragma unroll
        for (int j = 0; j < 4; ++j)
            M[i][j] = fmaxf(expf(l[j] - m), 1e-6f);
    }
    for (int it = 0; it < 20; ++it) {
#pragma unroll
        for (int i = 0; i < 4; ++i) {
            const float s = (M[i][0] + M[i][1]) + (M[i][2] + M[i][3]);
            const float inv = __builtin_amdgcn_rcpf(fmaxf(s, 1e-6f));
#pragma unroll
            for (int j = 0; j < 4; ++j) M[i][j] *= inv;
        }
#pragma unroll
        for (int j = 0; j < 4; ++j) {
            const float s = (M[0][j] + M[1][j]) + (M[2][j] + M[3][j]);
            const float inv = __builtin_amdgcn_rcpf(fmaxf(s, 1e-6f));
#pragma unroll
            for (int i = 0; i < 4; ++i) M[i][j] *= inv;
        }
    }

    float* out_pre  = out;                        // [NTOK][4]
    float* out_post = out + (size_t)NTOK * 4;     // [NTOK][4]
    float* out_res  = out + (size_t)NTOK * 8;     // [NTOK][16]
    if (gq == 0) {
        ((float4*)out_pre)[tk] = make_float4(hp[0], hp[1], hp[2], hp[3]);
    } else if (gq == 1) {
        ((float4*)out_post)[tk] = make_float4(hq[0], hq[1], hq[2], hq[3]);
    } else if (gq >= 4) {
        const int i = gq - 4;
        ((float4*)out_res)[tk * 4 + i] =
            make_float4(M[i][0], M[i][1], M[i][2], M[i][3]);
    }
}

// ---------------------------------------------------------------------------
extern "C" void kernel_launch(void* const* d_in, const int* in_sizes, int n_in,
                              void* d_out, int out_size, void* d_ws, size_t ws_size,
                              hipStream_t stream) {
    const float* x      = (const float*)d_in[0];   // (2,4096,4,2048) fp32
    const float* rms_w  = (const float*)d_in[1];   // (8192,)
    const float* w_pre  = (const float*)d_in[2];   // (4,8192)
    const float* w_post = (const float*)d_in[3];   // (4,8192)
    const float* w_res  = (const float*)d_in[4];   // (16,8192)
    const float* b_pre  = (const float*)d_in[5];   // (4,)
    const float* b_post = (const float*)d_in[6];   // (4,)
    const float* b_res  = (const float*)d_in[7];   // (4,4)
    const float* a_pre  = (const float*)d_in[8];   // scalar
    const float* a_post = (const float*)d_in[9];   // scalar
    const float* a_res  = (const float*)d_in[10];  // scalar
    float* out = (float*)d_out;

    // ws: Wc2 (32*6240 = 199680 floats) + part (32*8192*28) ~ 30.2 MB
    float* Wc2  = (float*)d_ws;
    float* part = (float*)d_ws + (size_t)NGRP * WLDN;

    combine_w<<<(NGRP * WLDN + TPB - 1) / TPB, TPB, 0, stream>>>(
        rms_w, w_pre, w_post, w_res, a_pre, a_post, a_res, Wc2);

    partial_k<<<dim3(NTOK / TOKB, NGRP), TPB, 0, stream>>>(x, Wc2, part);

    finalize_k<<<NTOK / 32, TPB, 0, stream>>>(part, b_pre, b_post, b_res, out);
}

// Round 9
// 91.003 us; speedup vs baseline: 7.7959x; 1.0951x over previous
//
#include <hip/hip_runtime.h>
#include <math.h>

// Problem constants (B=2, T=4096, n=4, D=2048)
#define DM      8192      // n*D flattened feature dim
#define NK      24        // 4 pre + 4 post + 16 res dot products
#define NACC    25        // + 1 for sum(x^2)
#define NTOK    8192      // B*T tokens
#define NGRP    32        // d-groups across blocks
#define DPG     256       // d per group (weights LDS-resident: 24 KB)
#define TPB     256
#define TOKB    128       // tokens per block (32 ts * 4 u)
#define UT      4         // tokens per thread
#define NCH     16        // chunks of 16 d; thread covers 4 d/chunk
#define KHN     12        // coefficients per kh half
#define PPT     28        // padded partials per token (25 used, float4-aligned)

// ---------------------------------------------------------------------------
// Kernel 1: Wc2[grp][k][dloc] = alpha_k * W_k[grp*256+dloc] * rms_w[...]
// k-major per group so partial_k can stage one linear 24 KB block.
// ---------------------------------------------------------------------------
__global__ void combine_w(const float* __restrict__ rms_w,
                          const float* __restrict__ w_pre,
                          const float* __restrict__ w_post,
                          const float* __restrict__ w_res,
                          const float* __restrict__ a_pre,
                          const float* __restrict__ a_post,
                          const float* __restrict__ a_res,
                          float* __restrict__ Wc2) {
    int idx = blockIdx.x * blockDim.x + threadIdx.x;
    if (idx >= NGRP * NK * DPG) return;
    const int grp  = idx / (NK * DPG);
    const int r    = idx - grp * (NK * DPG);
    const int k    = r / DPG;
    const int dloc = r - k * DPG;
    const int d    = grp * DPG + dloc;
    float w, a;
    if (k < 4)      { w = w_pre [(size_t)k       * DM + d]; a = a_pre[0];  }
    else if (k < 8) { w = w_post[(size_t)(k - 4) * DM + d]; a = a_post[0]; }
    else            { w = w_res [(size_t)(k - 8) * DM + d]; a = a_res[0];  }
    Wc2[idx] = a * w * rms_w[d];
}

// async global->LDS, 16B per lane (dest linear: wave-uniform base + lane*16)
__device__ __forceinline__ void load_lds16(const float* g, float* l) {
    __builtin_amdgcn_global_load_lds(
        (const __attribute__((address_space(1))) void*)g,
        (__attribute__((address_space(3))) void*)l, 16, 0, 0);
}

// ---------------------------------------------------------------------------
// Kernel 2: streaming partials. Block = 128 tokens x 256 d.
//  PROVEN-BEST structure (R6 bench: 92.1 us total). thread (ts,kh,dl):
//    tokens {tile*128 + ts + 32u}, coeff half kh*12..+12 (+ ss, both halves),
//    d-slice dl*4 per 16-d chunk. acc[4][13] = 52 regs, statically indexed.
//  __launch_bounds__(256,4): VGPR cap 128 — register floor is ~100; (256,5)
//  capped at 48 VGPR and spilled (R5: 619us). Ping-pong macro restructure
//  collapsed regalloc to 64 VGPR and spilled (R7: 709us). kq-4-way split
//  was neutral-negative (R8: 99.7us). Keep THIS loop body verbatim.
//  GRID IS (grp, tile): grp = blockIdx.x (fastest) so the ~1024 co-resident
//  blocks cover contiguous 32KB token rows -> sequential concurrent HBM
//  stream (DRAM row-buffer locality), instead of 1KB strips strided 32KB.
// part layout (token-major, padded): part[(grp*NTOK + token)*28 + c]
// ---------------------------------------------------------------------------
__global__ __launch_bounds__(TPB, 4) void partial_k(const float* __restrict__ x,
                                                    const float* __restrict__ Wc2,
                                                    float* __restrict__ part) {
    __shared__ __align__(16) float wlds[NK * DPG];   // [24][256] k-major, 24 KB

    const int t    = threadIdx.x;
    const int grp  = blockIdx.x;          // 0..31  (fastest -> contiguous rows)
    const int tile = blockIdx.y;          // 0..63

    // ---- stage weights once: 24 KB linear ----
    const float* wsrc = Wc2 + (size_t)grp * (NK * DPG);
#pragma unroll
    for (int ld = 0; ld < 6; ++ld) {
        const int e = (t + ld * TPB) * 4;
        load_lds16(wsrc + e, &wlds[e]);
    }

    const int dl   = t & 3;               // d sublane 0..3
    const int kh   = (t >> 2) & 1;        // coefficient half 0..1
    const int ts   = t >> 3;              // token slot 0..31
    const int tok0 = tile * TOKB + ts;    // + 32*u
    const float* xp = x + (size_t)tok0 * DM + grp * DPG + dl * 4;

    float acc[UT][13];
#pragma unroll
    for (int u = 0; u < UT; ++u)
#pragma unroll
        for (int kk = 0; kk < 13; ++kk) acc[u][kk] = 0.0f;

    __syncthreads();                      // weights staged (drains vmcnt)

    float xc[UT][4], xn[UT][4];
#pragma unroll
    for (int u = 0; u < UT; ++u) {
        const float4 v = *(const float4*)(xp + (size_t)u * 32 * DM);
        xc[u][0] = v.x; xc[u][1] = v.y; xc[u][2] = v.z; xc[u][3] = v.w;
    }

    for (int c = 0; c < NCH; ++c) {
        if (c + 1 < NCH) {                // uniform branch: prefetch next chunk
#pragma unroll
            for (int u = 0; u < UT; ++u) {
                const float4 v = *(const float4*)(xp + (size_t)u * 32 * DM +
                                                  (c + 1) * 16);
                xn[u][0] = v.x; xn[u][1] = v.y; xn[u][2] = v.z; xn[u][3] = v.w;
            }
        }
        const float* wl = &wlds[kh * (KHN * DPG) + c * 16 + dl * 4];
#pragma unroll
        for (int kk = 0; kk < KHN; ++kk) {
            const float4 w4 = *(const float4*)(wl + kk * DPG);
#pragma unroll
            for (int u = 0; u < UT; ++u) {
                acc[u][kk] = fmaf(xc[u][0], w4.x, acc[u][kk]);
                acc[u][kk] = fmaf(xc[u][1], w4.y, acc[u][kk]);
                acc[u][kk] = fmaf(xc[u][2], w4.z, acc[u][kk]);
                acc[u][kk] = fmaf(xc[u][3], w4.w, acc[u][kk]);
            }
        }
#pragma unroll
        for (int u = 0; u < UT; ++u)      // ss on both kh halves (uniform)
#pragma unroll
            for (int e = 0; e < 4; ++e)
                acc[u][12] = fmaf(xc[u][e], xc[u][e], acc[u][12]);
        if (c + 1 < NCH) {
#pragma unroll
            for (int u = 0; u < UT; ++u)
#pragma unroll
                for (int e = 0; e < 4; ++e) xc[u][e] = xn[u][e];
        }
    }

    // ---- butterfly reduce over the 4 dl lanes ----
#pragma unroll
    for (int u = 0; u < UT; ++u)
#pragma unroll
        for (int kk = 0; kk < 13; ++kk) {
            float v = acc[u][kk];
            v += __shfl_xor(v, 1);
            v += __shfl_xor(v, 2);
            acc[u][kk] = v;
        }

    // ---- reshape via LDS into token-major [128][28] (static reg indices) ----
    __syncthreads();                      // done reading wlds
    float* red = wlds;
    if (dl == 0) {
#pragma unroll
        for (int u = 0; u < UT; ++u) {
            const int tloc = ts + 32 * u;
#pragma unroll
            for (int kk = 0; kk < KHN; ++kk)
                red[tloc * PPT + kh * KHN + kk] = acc[u][kk];
            if (kh == 0) red[tloc * PPT + 24] = acc[u][12];
        }
    }
    __syncthreads();

    // ---- block-copy 128*28 floats = 896 float4 (contiguous global write) ----
    float4* dst = (float4*)(part + ((size_t)grp * NTOK + (size_t)tile * TOKB) * PPT);
    const float4* srcv = (const float4*)red;
#pragma unroll
    for (int w = 0; w < 4; ++w) {
        const int i = t + w * TPB;
        if (i < (TOKB * PPT) / 4) dst[i] = srcv[i];
    }
}

// ---------------------------------------------------------------------------
// Kernel 3: finalize. Block = 32 tokens x 8 grp-octant lanes (256 blocks).
// ---------------------------------------------------------------------------
__global__ void finalize_k(const float* __restrict__ part,
                           const float* __restrict__ b_pre,
                           const float* __restrict__ b_post,
                           const float* __restrict__ b_res,
                           float* __restrict__ out) {
    const int t  = threadIdx.x;
    const int gq = t & 7;
    const int ts = t >> 3;
    const int tk = blockIdx.x * 32 + ts;

    float v[NACC];
#pragma unroll
    for (int c = 0; c < NACC; ++c) v[c] = 0.0f;
#pragma unroll
    for (int gg = 0; gg < 4; ++gg) {
        const int g = gq * 4 + gg;
        const float4* p4 = (const float4*)(part + ((size_t)g * NTOK + tk) * PPT);
        const float4 a0 = p4[0], a1 = p4[1], a2 = p4[2], a3 = p4[3];
        const float4 a4 = p4[4], a5 = p4[5], a6 = p4[6];
        v[0] += a0.x;  v[1] += a0.y;  v[2] += a0.z;  v[3] += a0.w;
        v[4] += a1.x;  v[5] += a1.y;  v[6] += a1.z;  v[7] += a1.w;
        v[8] += a2.x;  v[9] += a2.y;  v[10] += a2.z; v[11] += a2.w;
        v[12] += a3.x; v[13] += a3.y; v[14] += a3.z; v[15] += a3.w;
        v[16] += a4.x; v[17] += a4.y; v[18] += a4.z; v[19] += a4.w;
        v[20] += a5.x; v[21] += a5.y; v[22] += a5.z; v[23] += a5.w;
        v[24] += a6.x;                 // a6.yzw = pad, ignored
    }
#pragma unroll
    for (int c = 0; c < NACC; ++c) {
        float s = v[c];
        s += __shfl_xor(s, 1);
        s += __shfl_xor(s, 2);
        s += __shfl_xor(s, 4);
        v[c] = s;
    }

    const float rstd = rsqrtf(v[24] * (1.0f / (float)DM) + 1e-6f);

    float hp[4], hq[4];
#pragma unroll
    for (int j = 0; j < 4; ++j) {
        const float lp = fmaf(v[j], rstd, b_pre[j]);
        hp[j] = 1.0f / (1.0f + expf(-lp));
        const float lq = fmaf(v[4 + j], rstd, b_post[j]);
        hq[j] = 2.0f / (1.0f + expf(-lq));
    }

    // Sinkhorn-Knopp on 4x4, in registers; v_rcp_f32 for the 160 divides
    // (validated R7/R8: absmax identical 1.95e-3)
    float M[4][4];
#pragma unroll
    for (int i = 0; i < 4; ++i) {
        float l[4];
#pragma unroll
        for (int j = 0; j < 4; ++j)
            l[j] = fmaf(v[8 + i * 4 + j], rstd, b_res[i * 4 + j]);
        const float m = fmaxf(fmaxf(l[0], l[1]), fmaxf(l[2], l[3]));
#pragma unroll
        for (int j = 0; j < 4; ++j)
            M[i][j] = fmaxf(expf(l[j] - m), 1e-6f);
    }
    for (int it = 0; it < 20; ++it) {
#pragma unroll
        for (int i = 0; i < 4; ++i) {
            const float s = (M[i][0] + M[i][1]) + (M[i][2] + M[i][3]);
            const float inv = __builtin_amdgcn_rcpf(fmaxf(s, 1e-6f));
#pragma unroll
            for (int j = 0; j < 4; ++j) M[i][j] *= inv;
        }
#pragma unroll
        for (int j = 0; j < 4; ++j) {
            const float s = (M[0][j] + M[1][j]) + (M[2][j] + M[3][j]);
            const float inv = __builtin_amdgcn_rcpf(fmaxf(s, 1e-6f));
#pragma unroll
            for (int i = 0; i < 4; ++i) M[i][j] *= inv;
        }
    }

    float* out_pre  = out;                        // [NTOK][4]
    float* out_post = out + (size_t)NTOK * 4;     // [NTOK][4]
    float* out_res  = out + (size_t)NTOK * 8;     // [NTOK][16]
    if (gq == 0) {
        ((float4*)out_pre)[tk] = make_float4(hp[0], hp[1], hp[2], hp[3]);
    } else if (gq == 1) {
        ((float4*)out_post)[tk] = make_float4(hq[0], hq[1], hq[2], hq[3]);
    } else if (gq >= 4) {
        const int i = gq - 4;
        ((float4*)out_res)[tk * 4 + i] =
            make_float4(M[i][0], M[i][1], M[i][2], M[i][3]);
    }
}

// ---------------------------------------------------------------------------
extern "C" void kernel_launch(void* const* d_in, const int* in_sizes, int n_in,
                              void* d_out, int out_size, void* d_ws, size_t ws_size,
                              hipStream_t stream) {
    const float* x      = (const float*)d_in[0];   // (2,4096,4,2048) fp32
    const float* rms_w  = (const float*)d_in[1];   // (8192,)
    const float* w_pre  = (const float*)d_in[2];   // (4,8192)
    const float* w_post = (const float*)d_in[3];   // (4,8192)
    const float* w_res  = (const float*)d_in[4];   // (16,8192)
    const float* b_pre  = (const float*)d_in[5];   // (4,)
    const float* b_post = (const float*)d_in[6];   // (4,)
    const float* b_res  = (const float*)d_in[7];   // (4,4)
    const float* a_pre  = (const float*)d_in[8];   // scalar
    const float* a_post = (const float*)d_in[9];   // scalar
    const float* a_res  = (const float*)d_in[10];  // scalar
    float* out = (float*)d_out;

    // ws: Wc2 (196608 floats) + part (32*8192*28 = 7.34M floats) ~ 30.2 MB
    float* Wc2  = (float*)d_ws;
    float* part = (float*)d_ws + (size_t)NGRP * NK * DPG;

    combine_w<<<(NGRP * NK * DPG + TPB - 1) / TPB, TPB, 0, stream>>>(
        rms_w, w_pre, w_post, w_res, a_pre, a_post, a_res, Wc2);

    // grp fastest: co-resident blocks sweep contiguous token rows
    partial_k<<<dim3(NGRP, NTOK / TOKB), TPB, 0, stream>>>(x, Wc2, part);

    finalize_k<<<NTOK / 32, TPB, 0, stream>>>(part, b_pre, b_post, b_res, out);
}